// Round 1
// baseline (8318.797 us; speedup 1.0000x reference)
//
#include <hip/hip_runtime.h>

#define NN 100000          // N_NODES
#define ED 64              // EMB_DIM
#define NE 3200000         // N_EDGES
#define NW 4               // N_LAYERS + 1

__device__ __forceinline__ void atomAddF(float* p, float v) {
    // native global_atomic_add_f32 on CDNA
    unsafeAtomicAdd(p, v);
}

// softmax over the 4 attention weights -> attn[4]
__global__ void k_softmax(const float* __restrict__ w, float* __restrict__ attn) {
    float m = fmaxf(fmaxf(w[0], w[1]), fmaxf(w[2], w[3]));
    float e0 = expf(w[0] - m), e1 = expf(w[1] - m), e2 = expf(w[2] - m), e3 = expf(w[3] - m);
    float s = e0 + e1 + e2 + e3;
    attn[0] = e0 / s; attn[1] = e1 / s; attn[2] = e2 / s; attn[3] = e3 / s;
}

// deg[dst[e]] += 1
__global__ void k_deg(const int* __restrict__ dst, float* __restrict__ deg) {
    int e = blockIdx.x * 256 + threadIdx.x;
    if (e < NE) atomAddF(&deg[dst[e]], 1.0f);
}

// deg -> rsqrt(deg) in place (0 where deg==0)
__global__ void k_dinv(float* __restrict__ deg) {
    int n = blockIdx.x * 256 + threadIdx.x;
    if (n < NN) {
        float d = deg[n];
        deg[n] = (d > 0.0f) ? rsqrtf(d) : 0.0f;
    }
}

// coef[e] = dinv[src]*dinv[dst]*exp(scale*attr)
__global__ void k_coef(const int* __restrict__ src, const int* __restrict__ dst,
                       const float* __restrict__ attr, const float* __restrict__ scale,
                       const float* __restrict__ dinv, float* __restrict__ coef) {
    int e = blockIdx.x * 256 + threadIdx.x;
    if (e < NE) {
        coef[e] = dinv[src[e]] * dinv[dst[e]] * expf(scale[0] * attr[e]);
    }
}

// out0 = emb0 ; acc = attn[0]*emb0   (float4 over NN*ED)
__global__ void k_init(const float* __restrict__ emb, const float* __restrict__ attn,
                       float* __restrict__ out0, float* __restrict__ acc) {
    int i = blockIdx.x * 256 + threadIdx.x;   // float4 index, grid sized exactly
    float4 v = reinterpret_cast<const float4*>(emb)[i];
    reinterpret_cast<float4*>(out0)[i] = v;
    float a = attn[0];
    float4 w = make_float4(v.x * a, v.y * a, v.z * a, v.w * a);
    reinterpret_cast<float4*>(acc)[i] = w;
}

// y[dst] += x[src] * coef ; 16 lanes per edge, one float4 chunk each
__global__ void k_scatter(const int* __restrict__ src, const int* __restrict__ dst,
                          const float* __restrict__ coef,
                          const float* __restrict__ x, float* __restrict__ y) {
    unsigned tid = blockIdx.x * 256u + threadIdx.x;   // grid = NE*16 exactly
    unsigned e = tid >> 4;
    unsigned c = tid & 15u;
    int s = src[e];
    int d = dst[e];
    float k = coef[e];
    float4 v = reinterpret_cast<const float4*>(x + (size_t)s * ED)[c];
    float* o = y + (size_t)d * ED + c * 4u;
    atomAddF(o + 0, v.x * k);
    atomAddF(o + 1, v.y * k);
    atomAddF(o + 2, v.z * k);
    atomAddF(o + 3, v.w * k);
}

// acc += attn[l] * x   (float4 over NN*ED)
__global__ void k_acc(const float* __restrict__ x, const float* __restrict__ attn,
                      int l, float* __restrict__ acc) {
    int i = blockIdx.x * 256 + threadIdx.x;
    float a = attn[l];
    float4 v = reinterpret_cast<const float4*>(x)[i];
    float4 w = reinterpret_cast<float4*>(acc)[i];
    w.x += a * v.x; w.y += a * v.y; w.z += a * v.z; w.w += a * v.w;
    reinterpret_cast<float4*>(acc)[i] = w;
}

extern "C" void kernel_launch(void* const* d_in, const int* in_sizes, int n_in,
                              void* d_out, int out_size, void* d_ws, size_t ws_size,
                              hipStream_t stream) {
    const float* emb   = (const float*)d_in[0];   // [NN, ED]
    const float* attw  = (const float*)d_in[1];   // [4]
    const float* scale = (const float*)d_in[2];   // [1]
    const float* attr  = (const float*)d_in[3];   // [NE]
    const int*   ei    = (const int*)d_in[4];     // [2, NE] int32
    const int* src = ei;
    const int* dst = ei + NE;

    float* out0 = (float*)d_out;                  // emb0 chunk
    float* acc  = out0 + (size_t)NN * ED;         // weighted-sum chunk

    char* ws = (char*)d_ws;
    size_t off = 0;
    float* attn = (float*)(ws + off); off += 256;
    float* deg  = (float*)(ws + off); off += ((size_t)NN * 4 + 255) & ~(size_t)255;
    float* coef = (float*)(ws + off); off += (size_t)NE * 4;
    float* x1   = (float*)(ws + off); off += (size_t)NN * ED * 4;
    float* x2   = (float*)(ws + off); off += (size_t)NN * ED * 4;

    const int EB = (NE + 255) / 256;              // edge-grid
    const int NB = (NN + 255) / 256;              // node-grid
    const int VB = (NN * ED / 4) / 256;           // float4 elementwise grid (exact)
    const int SB = (int)((size_t)NE * 16 / 256);  // scatter grid (exact)

    hipMemsetAsync(deg, 0, (size_t)NN * 4, stream);
    k_softmax<<<1, 1, 0, stream>>>(attw, attn);
    k_deg<<<EB, 256, 0, stream>>>(dst, deg);
    k_dinv<<<NB, 256, 0, stream>>>(deg);
    k_coef<<<EB, 256, 0, stream>>>(src, dst, attr, scale, deg, coef);
    k_init<<<VB, 256, 0, stream>>>(emb, attn, out0, acc);

    // layer 1: x1 = scatter(emb)
    hipMemsetAsync(x1, 0, (size_t)NN * ED * 4, stream);
    k_scatter<<<SB, 256, 0, stream>>>(src, dst, coef, emb, x1);
    k_acc<<<VB, 256, 0, stream>>>(x1, attn, 1, acc);

    // layer 2: x2 = scatter(x1)
    hipMemsetAsync(x2, 0, (size_t)NN * ED * 4, stream);
    k_scatter<<<SB, 256, 0, stream>>>(src, dst, coef, x1, x2);
    k_acc<<<VB, 256, 0, stream>>>(x2, attn, 2, acc);

    // layer 3: x1 = scatter(x2)
    hipMemsetAsync(x1, 0, (size_t)NN * ED * 4, stream);
    k_scatter<<<SB, 256, 0, stream>>>(src, dst, coef, x2, x1);
    k_acc<<<VB, 256, 0, stream>>>(x1, attn, 3, acc);
}

// Round 2
// 890.213 us; speedup vs baseline: 9.3447x; 9.3447x over previous
//
#include <hip/hip_runtime.h>

#define NN 100000          // N_NODES
#define ED 64              // EMB_DIM
#define NE 3200000         // N_EDGES

// softmax over the 4 attention weights -> attn[4]
__global__ void k_softmax(const float* __restrict__ w, float* __restrict__ attn) {
    float m = fmaxf(fmaxf(w[0], w[1]), fmaxf(w[2], w[3]));
    float e0 = expf(w[0] - m), e1 = expf(w[1] - m), e2 = expf(w[2] - m), e3 = expf(w[3] - m);
    float s = e0 + e1 + e2 + e3;
    attn[0] = e0 / s; attn[1] = e1 / s; attn[2] = e2 / s; attn[3] = e3 / s;
}

// degi[dst[e]] += 1  (int histogram)
__global__ void k_count(const int* __restrict__ dst, int* __restrict__ degi) {
    int e = blockIdx.x * 256 + threadIdx.x;
    if (e < NE) atomicAdd(&degi[dst[e]], 1);
}

// exclusive prefix sum of degi[NN] -> rowptr[NN] (row starts).
// single block, 1024 threads, shfl-scan per wave + 16-wave LDS combine.
__global__ void k_scan(const int* __restrict__ degi, int* __restrict__ rowptr) {
    __shared__ int wsum[16];
    __shared__ int carry_s;
    __shared__ int chunk_tot;
    const int tid = threadIdx.x, lane = tid & 63, wv = tid >> 6;
    if (tid == 0) carry_s = 0;
    __syncthreads();
    for (int base = 0; base < NN; base += 1024) {
        int i = base + tid;
        int v = (i < NN) ? degi[i] : 0;
        int x = v;
        #pragma unroll
        for (int o = 1; o < 64; o <<= 1) {
            int t = __shfl_up(x, o, 64);
            if (lane >= o) x += t;
        }
        if (lane == 63) wsum[wv] = x;
        __syncthreads();
        if (tid < 16) {
            int orig = wsum[tid];
            int t = orig;
            #pragma unroll
            for (int o = 1; o < 16; o <<= 1) {
                int u = __shfl_up(t, o, 64);
                if (tid >= o) t += u;
            }
            wsum[tid] = t - orig;            // exclusive wave offset
            if (tid == 15) chunk_tot = t;    // chunk total
        }
        __syncthreads();
        if (i < NN) rowptr[i] = carry_s + wsum[wv] + (x - v);  // exclusive scan
        __syncthreads();
        if (tid == 0) carry_s += chunk_tot;
        __syncthreads();
    }
}

// degi (int counts) -> rsqrt in place as float
__global__ void k_dinv(int* __restrict__ buf) {
    int n = blockIdx.x * 256 + threadIdx.x;
    if (n < NN) {
        int d = buf[n];
        float r = (d > 0) ? rsqrtf((float)d) : 0.0f;
        reinterpret_cast<float*>(buf)[n] = r;
    }
}

// CSR fill: for each edge, coef = dinv[src]*dinv[dst]*exp(scale*attr);
// slot p = rowptr[dst]++ (atomic). Packs (src, coef) into 8B.
// NOTE: after this kernel rowptr[n] == end-of-row n (= old rowptr[n+1]).
__global__ void k_fill(const int* __restrict__ src, const int* __restrict__ dst,
                       const float* __restrict__ attr, const float* __restrict__ scale,
                       const float* __restrict__ dinv,
                       int* __restrict__ rptr, float2* __restrict__ csr) {
    int e = blockIdx.x * 256 + threadIdx.x;
    if (e >= NE) return;
    int s = src[e], d = dst[e];
    float c = dinv[s] * dinv[d] * expf(scale[0] * attr[e]);
    int p = atomicAdd(&rptr[d], 1);
    csr[p] = make_float2(__int_as_float(s), c);
}

// acc = attn[0] * emb   (float4 over NN*ED, exact grid)
__global__ void k_init_acc(const float* __restrict__ emb, const float* __restrict__ attn,
                           float* __restrict__ acc) {
    int i = blockIdx.x * 256 + threadIdx.x;
    float a = attn[0];
    float4 v = reinterpret_cast<const float4*>(emb)[i];
    reinterpret_cast<float4*>(acc)[i] = make_float4(v.x * a, v.y * a, v.z * a, v.w * a);
}

// out0 = emb  (float4, exact grid)
__global__ void k_copy(const float* __restrict__ emb, float* __restrict__ out0) {
    int i = blockIdx.x * 256 + threadIdx.x;
    reinterpret_cast<float4*>(out0)[i] = reinterpret_cast<const float4*>(emb)[i];
}

// Gather propagation: one wave per node, lane owns one of 64 dims.
// Row n spans [ n?rowptr[n-1]:0 , rowptr[n] ) in post-fill convention.
// y[n] = sum_j coef_j * x[src_j] ; acc[n] += attn[l] * y[n]
template <bool WRITE_Y>
__global__ void __launch_bounds__(256) k_gather(const int* __restrict__ rowptr,
                                                const float2* __restrict__ csr,
                                                const float* __restrict__ x,
                                                float* __restrict__ y,
                                                float* __restrict__ acc,
                                                const float* __restrict__ attn, int l) {
    int gt = blockIdx.x * 256 + threadIdx.x;   // grid = NN*64 exactly
    int nid = gt >> 6;
    int lane = gt & 63;
    int end = rowptr[nid];
    int beg = (nid > 0) ? rowptr[nid - 1] : 0;
    float a = 0.0f;
    int j = beg;
    for (; j + 2 <= end; j += 2) {             // unroll 2 for MLP
        float2 p0 = csr[j], p1 = csr[j + 1];
        a += p0.y * x[(size_t)__float_as_int(p0.x) * ED + lane];
        a += p1.y * x[(size_t)__float_as_int(p1.x) * ED + lane];
    }
    if (j < end) {
        float2 p = csr[j];
        a += p.y * x[(size_t)__float_as_int(p.x) * ED + lane];
    }
    size_t o = (size_t)nid * ED + lane;
    if (WRITE_Y) y[o] = a;
    acc[o] += attn[l] * a;
}

extern "C" void kernel_launch(void* const* d_in, const int* in_sizes, int n_in,
                              void* d_out, int out_size, void* d_ws, size_t ws_size,
                              hipStream_t stream) {
    const float* emb   = (const float*)d_in[0];   // [NN, ED]
    const float* attw  = (const float*)d_in[1];   // [4]
    const float* scale = (const float*)d_in[2];   // [1]
    const float* attr  = (const float*)d_in[3];   // [NE]
    const int*   ei    = (const int*)d_in[4];     // [2, NE] (int32 on device)
    const int* src = ei;
    const int* dst = ei + NE;

    float* out0 = (float*)d_out;                  // emb0 chunk [NN*ED]
    float* acc  = out0 + (size_t)NN * ED;         // weighted-sum chunk [NN*ED]

    // workspace layout (~26.5 MB)
    char* ws = (char*)d_ws;
    size_t off = 0;
    float*  attn   = (float*)(ws + off);  off += 256;
    int*    degi   = (int*)(ws + off);    off += ((size_t)NN * 4 + 255) & ~(size_t)255;  // becomes dinv (float) in place
    int*    rowptr = (int*)(ws + off);    off += ((size_t)NN * 4 + 255) & ~(size_t)255;
    float2* csr    = (float2*)(ws + off); off += (size_t)NE * 8;
    float*  x1     = (float*)(ws + off);  off += (size_t)NN * ED * 4;
    float*  x2     = out0;                // out0 region is dead until the end -> use as x2 scratch

    const int EB = (NE + 255) / 256;      // 12500
    const int NB = (NN + 255) / 256;      // 391
    const int VB = (NN * ED / 4) / 256;   // 6250 (exact)
    const int GB = (NN * ED) / 256;       // 25000 (exact)

    hipMemsetAsync(degi, 0, (size_t)NN * 4, stream);
    k_softmax<<<1, 1, 0, stream>>>(attw, attn);
    k_count<<<EB, 256, 0, stream>>>(dst, degi);
    k_scan<<<1, 1024, 0, stream>>>(degi, rowptr);
    k_dinv<<<NB, 256, 0, stream>>>(degi);
    k_fill<<<EB, 256, 0, stream>>>(src, dst, attr, scale, (const float*)degi, rowptr, csr);

    k_init_acc<<<VB, 256, 0, stream>>>(emb, attn, acc);

    // layer 1: x1 = P(emb);  acc += attn[1]*x1
    k_gather<true><<<GB, 256, 0, stream>>>(rowptr, csr, emb, x1, acc, attn, 1);
    // layer 2: x2 = P(x1);   acc += attn[2]*x2   (x2 lives in out0 region)
    k_gather<true><<<GB, 256, 0, stream>>>(rowptr, csr, x1, x2, acc, attn, 2);
    // layer 3: acc += attn[3]*P(x2)              (no y write)
    k_gather<false><<<GB, 256, 0, stream>>>(rowptr, csr, x2, nullptr, acc, attn, 3);

    // finally materialize out0 = emb (after x2 scratch use is done)
    k_copy<<<VB, 256, 0, stream>>>(emb, out0);
}

// Round 3
// 653.198 us; speedup vs baseline: 12.7355x; 1.3629x over previous
//
#include <hip/hip_runtime.h>

#define NN 100000          // N_NODES
#define ED 64              // EMB_DIM
#define NE 3200000         // N_EDGES
#define SCAN_BLOCKS ((NN + 1023) / 1024)   // 98

__device__ __forceinline__ float b2f(unsigned short u) {
    return __uint_as_float(((unsigned)u) << 16);
}
__device__ __forceinline__ unsigned short f2b(float f) {
    unsigned x = __float_as_uint(f);
    return (unsigned short)((x + 0x7FFFu + ((x >> 16) & 1u)) >> 16);  // RNE
}

// softmax over the 4 attention weights -> attn[4]
__global__ void k_softmax(const float* __restrict__ w, float* __restrict__ attn) {
    float m = fmaxf(fmaxf(w[0], w[1]), fmaxf(w[2], w[3]));
    float e0 = expf(w[0] - m), e1 = expf(w[1] - m), e2 = expf(w[2] - m), e3 = expf(w[3] - m);
    float s = e0 + e1 + e2 + e3;
    attn[0] = e0 / s; attn[1] = e1 / s; attn[2] = e2 / s; attn[3] = e3 / s;
}

// degi[dst[e]] += 1 (int histogram), int4 vectorized. grid = NE/4/256 = 3125 exact
__global__ void k_count(const int* __restrict__ dst, int* __restrict__ degi) {
    int i = blockIdx.x * 256 + threadIdx.x;
    int4 d = reinterpret_cast<const int4*>(dst)[i];
    atomicAdd(&degi[d.x], 1); atomicAdd(&degi[d.y], 1);
    atomicAdd(&degi[d.z], 1); atomicAdd(&degi[d.w], 1);
}

// phase 1: per-block (1024 elems) exclusive scan + block sums
__global__ void k_scan1(const int* __restrict__ degi, int* __restrict__ rowptr,
                        int* __restrict__ bsum) {
    __shared__ int wsum[16];
    const int tid = threadIdx.x, lane = tid & 63, wv = tid >> 6;
    int i = blockIdx.x * 1024 + tid;
    int v = (i < NN) ? degi[i] : 0;
    int x = v;
    #pragma unroll
    for (int o = 1; o < 64; o <<= 1) { int t = __shfl_up(x, o, 64); if (lane >= o) x += t; }
    if (lane == 63) wsum[wv] = x;
    __syncthreads();
    if (tid < 16) {
        int orig = wsum[tid]; int t = orig;
        #pragma unroll
        for (int o = 1; o < 16; o <<= 1) { int u = __shfl_up(t, o, 64); if (tid >= o) t += u; }
        wsum[tid] = t - orig;
        if (tid == 15) bsum[blockIdx.x] = t;
    }
    __syncthreads();
    if (i < NN) rowptr[i] = wsum[wv] + (x - v);
}

// phase 2: exclusive scan of bsum[SCAN_BLOCKS] (<=128), one wave
__global__ void k_scan2(int* __restrict__ bsum) {
    int lane = threadIdx.x;  // 64 threads
    int v0 = (lane < SCAN_BLOCKS) ? bsum[lane] : 0;
    int v1 = (64 + lane < SCAN_BLOCKS) ? bsum[64 + lane] : 0;
    int s0 = v0;
    #pragma unroll
    for (int o = 1; o < 64; o <<= 1) { int t = __shfl_up(s0, o, 64); if (lane >= o) s0 += t; }
    int tot0 = __shfl(s0, 63, 64);
    int s1 = v1;
    #pragma unroll
    for (int o = 1; o < 64; o <<= 1) { int t = __shfl_up(s1, o, 64); if (lane >= o) s1 += t; }
    if (lane < SCAN_BLOCKS) bsum[lane] = s0 - v0;
    if (64 + lane < SCAN_BLOCKS) bsum[64 + lane] = tot0 + s1 - v1;
}

// phase 3: add block offsets
__global__ void k_scan3(int* __restrict__ rowptr, const int* __restrict__ bsum) {
    int i = blockIdx.x * 1024 + threadIdx.x;
    if (i < NN) rowptr[i] += bsum[blockIdx.x];
}

// degi (int counts) -> rsqrt in place as float
__global__ void k_dinv(int* __restrict__ buf) {
    int n = blockIdx.x * 256 + threadIdx.x;
    if (n < NN) {
        int d = buf[n];
        reinterpret_cast<float*>(buf)[n] = (d > 0) ? rsqrtf((float)d) : 0.0f;
    }
}

// CSR fill: coef = dinv[src]*dinv[dst]*exp(scale*attr); slot = rowptr[dst]++.
// After this kernel rowptr[n] == end-of-row n.
__global__ void k_fill(const int* __restrict__ src, const int* __restrict__ dst,
                       const float* __restrict__ attr, const float* __restrict__ scale,
                       const float* __restrict__ dinv,
                       int* __restrict__ rptr, float2* __restrict__ csr) {
    int e = blockIdx.x * 256 + threadIdx.x;
    if (e >= NE) return;
    int s = src[e], d = dst[e];
    float c = dinv[s] * dinv[d] * expf(scale[0] * attr[e]);
    int p = atomicAdd(&rptr[d], 1);
    csr[p] = make_float2(__int_as_float(s), c);
}

// x0 = bf16(emb), float4->ushort4. grid = NN*ED/4/256 = 6250 exact
__global__ void k_prep(const float* __restrict__ emb, unsigned short* __restrict__ x0) {
    int i = blockIdx.x * 256 + threadIdx.x;
    float4 e = reinterpret_cast<const float4*>(emb)[i];
    ushort4 u;
    u.x = f2b(e.x); u.y = f2b(e.y); u.z = f2b(e.z); u.w = f2b(e.w);
    reinterpret_cast<ushort4*>(x0)[i] = u;
}

// Gather propagation: one wave per node, lane owns one dim. bf16 x.
// ACC=false: y[n] = bf16(sum); ACC=true: acc[n] += attn[3]*sum (f32)
template <bool ACC>
__global__ void __launch_bounds__(256) k_gather(const int* __restrict__ rowptr,
        const float2* __restrict__ csr, const unsigned short* __restrict__ x,
        unsigned short* __restrict__ y, float* __restrict__ acc,
        const float* __restrict__ attn) {
    int gt = blockIdx.x * 256 + threadIdx.x;   // grid = NN*64/256 = 25000 exact
    int nid = gt >> 6;
    int lane = gt & 63;
    int end = rowptr[nid];
    int beg = nid ? rowptr[nid - 1] : 0;
    float a = 0.0f;
    int j = beg;
    for (; j + 4 <= end; j += 4) {
        float2 p0 = csr[j], p1 = csr[j + 1], p2 = csr[j + 2], p3 = csr[j + 3];
        unsigned short u0 = x[(size_t)__float_as_int(p0.x) * ED + lane];
        unsigned short u1 = x[(size_t)__float_as_int(p1.x) * ED + lane];
        unsigned short u2 = x[(size_t)__float_as_int(p2.x) * ED + lane];
        unsigned short u3 = x[(size_t)__float_as_int(p3.x) * ED + lane];
        a += p0.y * b2f(u0); a += p1.y * b2f(u1);
        a += p2.y * b2f(u2); a += p3.y * b2f(u3);
    }
    for (; j < end; ++j) {
        float2 p = csr[j];
        a += p.y * b2f(x[(size_t)__float_as_int(p.x) * ED + lane]);
    }
    if (ACC) {
        size_t o = (size_t)nid * ED + lane;
        acc[o] += attn[3] * a;
    } else {
        y[(size_t)nid * ED + lane] = f2b(a);
    }
}

// out0 = emb ; acc = a0*emb + a1*y1 + a2*y2   (float4 / ushort4)
__global__ void k_combine3(const float* __restrict__ emb, const unsigned short* __restrict__ y1,
                           const unsigned short* __restrict__ y2, const float* __restrict__ attn,
                           float* __restrict__ out0, float* __restrict__ acc) {
    int i = blockIdx.x * 256 + threadIdx.x;    // float4 index, 6250 blocks exact
    float4 e = reinterpret_cast<const float4*>(emb)[i];
    ushort4 a1 = reinterpret_cast<const ushort4*>(y1)[i];
    ushort4 a2 = reinterpret_cast<const ushort4*>(y2)[i];
    float w0 = attn[0], w1 = attn[1], w2 = attn[2];
    float4 r;
    r.x = w0 * e.x + w1 * b2f(a1.x) + w2 * b2f(a2.x);
    r.y = w0 * e.y + w1 * b2f(a1.y) + w2 * b2f(a2.y);
    r.z = w0 * e.z + w1 * b2f(a1.z) + w2 * b2f(a2.z);
    r.w = w0 * e.w + w1 * b2f(a1.w) + w2 * b2f(a2.w);
    reinterpret_cast<float4*>(out0)[i] = e;
    reinterpret_cast<float4*>(acc)[i] = r;
}

extern "C" void kernel_launch(void* const* d_in, const int* in_sizes, int n_in,
                              void* d_out, int out_size, void* d_ws, size_t ws_size,
                              hipStream_t stream) {
    const float* emb   = (const float*)d_in[0];   // [NN, ED]
    const float* attw  = (const float*)d_in[1];   // [4]
    const float* scale = (const float*)d_in[2];   // [1]
    const float* attr  = (const float*)d_in[3];   // [NE]
    const int*   ei    = (const int*)d_in[4];     // [2, NE] int32 on device
    const int* src = ei;
    const int* dst = ei + NE;

    float* out0 = (float*)d_out;                  // emb0 chunk [NN*ED]
    float* acc  = out0 + (size_t)NN * ED;         // weighted-sum chunk [NN*ED]

    // workspace layout (~65 MB)
    char* ws = (char*)d_ws;
    size_t off = 0;
    float*  attn   = (float*)(ws + off);  off += 256;
    int*    degi   = (int*)(ws + off);    off += ((size_t)NN * 4 + 255) & ~(size_t)255;  // becomes dinv (f32)
    int*    rowptr = (int*)(ws + off);    off += ((size_t)NN * 4 + 255) & ~(size_t)255;
    int*    bsum   = (int*)(ws + off);    off += 512;
    float2* csr    = (float2*)(ws + off); off += (size_t)NE * 8;
    unsigned short* x0 = (unsigned short*)(ws + off); off += (size_t)NN * ED * 2;
    unsigned short* y1 = (unsigned short*)(ws + off); off += (size_t)NN * ED * 2;
    unsigned short* y2 = (unsigned short*)(ws + off); off += (size_t)NN * ED * 2;

    const int EB = (NE + 255) / 256;       // 12500
    const int NB = (NN + 255) / 256;       // 391
    const int VB = (NN * ED / 4) / 256;    // 6250 exact
    const int GB = (NN * ED) / 256;        // 25000 exact
    const int CB = (NE / 4) / 256;         // 3125 exact

    hipMemsetAsync(degi, 0, (size_t)NN * 4, stream);
    k_softmax<<<1, 1, 0, stream>>>(attw, attn);
    k_count<<<CB, 256, 0, stream>>>(dst, degi);
    k_scan1<<<SCAN_BLOCKS, 1024, 0, stream>>>(degi, rowptr, bsum);
    k_scan2<<<1, 64, 0, stream>>>(bsum);
    k_scan3<<<SCAN_BLOCKS, 1024, 0, stream>>>(rowptr, bsum);
    k_dinv<<<NB, 256, 0, stream>>>(degi);
    k_fill<<<EB, 256, 0, stream>>>(src, dst, attr, scale, (const float*)degi, rowptr, csr);

    k_prep<<<VB, 256, 0, stream>>>(emb, x0);

    // layer 1: y1 = P(x0)
    k_gather<false><<<GB, 256, 0, stream>>>(rowptr, csr, x0, y1, nullptr, attn);
    // layer 2: y2 = P(y1)
    k_gather<false><<<GB, 256, 0, stream>>>(rowptr, csr, y1, y2, nullptr, attn);
    // out0 = emb ; acc = a0*emb + a1*y1 + a2*y2
    k_combine3<<<VB, 256, 0, stream>>>(emb, y1, y2, attn, out0, acc);
    // layer 3: acc += attn[3] * P(y2)
    k_gather<true><<<GB, 256, 0, stream>>>(rowptr, csr, y2, nullptr, acc, attn);
}

// Round 4
// 651.734 us; speedup vs baseline: 12.7641x; 1.0022x over previous
//
#include <hip/hip_runtime.h>

#define NN 100000          // N_NODES
#define ED 64              // EMB_DIM
#define NE 3200000         // N_EDGES
#define SCAN_BLOCKS ((NN + 1023) / 1024)   // 98
#define BSH 9                              // log2 nodes per bucket
#define BNODES 512
#define NBUCK ((NN + BNODES - 1) / BNODES) // 196
#define CHUNK 8192
#define PTH 512

__device__ __forceinline__ float b2f(unsigned short u) {
    return __uint_as_float(((unsigned)u) << 16);
}
__device__ __forceinline__ unsigned short f2b(float f) {
    unsigned x = __float_as_uint(f);
    return (unsigned short)((x + 0x7FFFu + ((x >> 16) & 1u)) >> 16);  // RNE
}
// non-temporal 8B load of a csr entry (keep the stream out of L2)
__device__ __forceinline__ float2 ldnt(const float2* p) {
    unsigned long long v = __builtin_nontemporal_load(reinterpret_cast<const unsigned long long*>(p));
    return make_float2(__uint_as_float((unsigned)v), __uint_as_float((unsigned)(v >> 32)));
}

__global__ void k_softmax(const float* __restrict__ w, float* __restrict__ attn) {
    float m = fmaxf(fmaxf(w[0], w[1]), fmaxf(w[2], w[3]));
    float e0 = expf(w[0] - m), e1 = expf(w[1] - m), e2 = expf(w[2] - m), e3 = expf(w[3] - m);
    float s = e0 + e1 + e2 + e3;
    attn[0] = e0 / s; attn[1] = e1 / s; attn[2] = e2 / s; attn[3] = e3 / s;
}

// per-node degree histogram, int4 vectorized. grid = NE/4/256 = 3125 exact
__global__ void k_count(const int* __restrict__ dst, int* __restrict__ degi) {
    int i = blockIdx.x * 256 + threadIdx.x;
    int4 d = reinterpret_cast<const int4*>(dst)[i];
    atomicAdd(&degi[d.x], 1); atomicAdd(&degi[d.y], 1);
    atomicAdd(&degi[d.z], 1); atomicAdd(&degi[d.w], 1);
}

// 3-phase exclusive scan of degi -> rowptr (row starts)
__global__ void k_scan1(const int* __restrict__ degi, int* __restrict__ rowptr,
                        int* __restrict__ bsum) {
    __shared__ int wsum[16];
    const int tid = threadIdx.x, lane = tid & 63, wv = tid >> 6;
    int i = blockIdx.x * 1024 + tid;
    int v = (i < NN) ? degi[i] : 0;
    int x = v;
    #pragma unroll
    for (int o = 1; o < 64; o <<= 1) { int t = __shfl_up(x, o, 64); if (lane >= o) x += t; }
    if (lane == 63) wsum[wv] = x;
    __syncthreads();
    if (tid < 16) {
        int orig = wsum[tid]; int t = orig;
        #pragma unroll
        for (int o = 1; o < 16; o <<= 1) { int u = __shfl_up(t, o, 64); if (tid >= o) t += u; }
        wsum[tid] = t - orig;
        if (tid == 15) bsum[blockIdx.x] = t;
    }
    __syncthreads();
    if (i < NN) rowptr[i] = wsum[wv] + (x - v);
}

__global__ void k_scan2(int* __restrict__ bsum) {
    int lane = threadIdx.x;  // 64 threads
    int v0 = (lane < SCAN_BLOCKS) ? bsum[lane] : 0;
    int v1 = (64 + lane < SCAN_BLOCKS) ? bsum[64 + lane] : 0;
    int s0 = v0;
    #pragma unroll
    for (int o = 1; o < 64; o <<= 1) { int t = __shfl_up(s0, o, 64); if (lane >= o) s0 += t; }
    int tot0 = __shfl(s0, 63, 64);
    int s1 = v1;
    #pragma unroll
    for (int o = 1; o < 64; o <<= 1) { int t = __shfl_up(s1, o, 64); if (lane >= o) s1 += t; }
    if (lane < SCAN_BLOCKS) bsum[lane] = s0 - v0;
    if (64 + lane < SCAN_BLOCKS) bsum[64 + lane] = tot0 + s1 - v1;
}

__global__ void k_scan3(int* __restrict__ rowptr, const int* __restrict__ bsum) {
    int i = blockIdx.x * 1024 + threadIdx.x;
    if (i < NN) rowptr[i] += bsum[blockIdx.x];
}

__global__ void k_dinv(int* __restrict__ buf) {
    int n = blockIdx.x * 256 + threadIdx.x;
    if (n < NN) {
        int d = buf[n];
        reinterpret_cast<float*>(buf)[n] = (d > 0) ? rsqrtf((float)d) : 0.0f;
    }
}

// bucket write cursors = bucket-start offsets in CSR order
__global__ void k_bcur(const int* __restrict__ rowptr, int* __restrict__ gcur) {
    int b = threadIdx.x;  // 256 threads, NBUCK used
    if (b < NBUCK) gcur[b] = rowptr[b * BNODES];
}

// pass 1: partition edges into dst-buckets with LDS staging + coalesced flush.
// entry u64 = (coef f32) << 32 | (dst_local 9b) << 17 | (src 17b)
__global__ void __launch_bounds__(PTH) k_part(const int* __restrict__ src,
        const int* __restrict__ dst, const float* __restrict__ attr,
        const float* __restrict__ scale, const float* __restrict__ dinv,
        int* __restrict__ gcur, unsigned long long* __restrict__ part) {
    __shared__ unsigned long long stage[CHUNK];   // 64 KiB
    __shared__ int hist[NBUCK];                   // histogram, then intra-chunk cursor
    __shared__ int lstart[NBUCK + 1];
    __shared__ int gbase[NBUCK];
    __shared__ unsigned char bkof[CHUNK];         // 8 KiB
    const int tid = threadIdx.x;
    const int base = blockIdx.x * CHUNK;
    const int n = min(CHUNK, NE - base);
    for (int i = tid; i < NBUCK; i += PTH) hist[i] = 0;
    __syncthreads();
    for (int i = tid; i < n; i += PTH) atomicAdd(&hist[dst[base + i] >> BSH], 1);
    __syncthreads();
    if (tid < 64) {                                // exclusive scan of hist
        int carry = 0;
        #pragma unroll
        for (int g = 0; g < 4; ++g) {              // 4*64 >= NBUCK
            int b = g * 64 + tid;
            int v = (b < NBUCK) ? hist[b] : 0;
            int s = v;
            #pragma unroll
            for (int o = 1; o < 64; o <<= 1) { int t = __shfl_up(s, o, 64); if (tid >= o) s += t; }
            if (b < NBUCK) lstart[b] = carry + s - v;
            carry += __shfl(s, 63, 64);
        }
        if (tid == 0) lstart[NBUCK] = n;
    }
    __syncthreads();
    for (int b = tid; b < NBUCK; b += PTH) {       // reserve global segments
        int cnt = lstart[b + 1] - lstart[b];
        gbase[b] = atomicAdd(&gcur[b], cnt);
        hist[b] = lstart[b];                       // local cursor
    }
    __syncthreads();
    float sc = scale[0];
    for (int i = tid; i < n; i += PTH) {           // compute + LDS scatter
        int e = base + i;
        int s = src[e], d = dst[e];
        float c = dinv[s] * dinv[d] * expf(sc * attr[e]);
        int bk = d >> BSH;
        int p = atomicAdd(&hist[bk], 1);
        stage[p] = ((unsigned long long)__float_as_uint(c) << 32)
                 | (unsigned)(s | ((d & (BNODES - 1)) << 17));
        bkof[p] = (unsigned char)bk;
    }
    __syncthreads();
    for (int i = tid; i < n; i += PTH) {           // coalesced flush
        int bk = bkof[i];
        part[(size_t)gbase[bk] + (i - lstart[bk])] = stage[i];
    }
}

// pass 2: per-bucket exact placement; random writes stay in one L2-hot span
__global__ void __launch_bounds__(512) k_place(const int* __restrict__ rowptr,
        const unsigned long long* __restrict__ part, float2* __restrict__ csr) {
    __shared__ int cur[BNODES];
    const int b = blockIdx.x;                      // NBUCK blocks
    const int node0 = b * BNODES;
    const int tid = threadIdx.x;
    int node = node0 + tid;
    cur[tid] = (node < NN) ? rowptr[node] : 0;
    const int rs = rowptr[node0];
    const int re = (node0 + BNODES < NN) ? rowptr[node0 + BNODES] : NE;
    __syncthreads();
    for (int j = rs + tid; j < re; j += 512) {
        unsigned long long v = part[j];
        unsigned lo = (unsigned)v;
        int s  = lo & 0x1FFFF;
        int dl = (lo >> 17) & (BNODES - 1);
        float c = __uint_as_float((unsigned)(v >> 32));
        int p = atomicAdd(&cur[dl], 1);
        csr[p] = make_float2(__int_as_float(s), c);
    }
}

// x0 = bf16(emb). grid = NN*ED/4/256 = 6250 exact
__global__ void k_prep(const float* __restrict__ emb, unsigned short* __restrict__ x0) {
    int i = blockIdx.x * 256 + threadIdx.x;
    float4 e = reinterpret_cast<const float4*>(emb)[i];
    ushort4 u;
    u.x = f2b(e.x); u.y = f2b(e.y); u.z = f2b(e.z); u.w = f2b(e.w);
    reinterpret_cast<ushort4*>(x0)[i] = u;
}

// gather: one wave per node, lane owns one dim. nt csr stream.
template <bool ACC>
__global__ void __launch_bounds__(256) k_gather(const int* __restrict__ rowptr,
        const float2* __restrict__ csr, const unsigned short* __restrict__ x,
        unsigned short* __restrict__ y, float* __restrict__ acc,
        const float* __restrict__ attn) {
    int gt = blockIdx.x * 256 + threadIdx.x;   // grid = NN*64/256 = 25000 exact
    int nid = gt >> 6;
    int lane = gt & 63;
    int beg = rowptr[nid];
    int end = (nid < NN - 1) ? rowptr[nid + 1] : NE;
    float a = 0.0f;
    int j = beg;
    for (; j + 4 <= end; j += 4) {
        float2 p0 = ldnt(csr + j),     p1 = ldnt(csr + j + 1);
        float2 p2 = ldnt(csr + j + 2), p3 = ldnt(csr + j + 3);
        unsigned short u0 = x[(size_t)__float_as_int(p0.x) * ED + lane];
        unsigned short u1 = x[(size_t)__float_as_int(p1.x) * ED + lane];
        unsigned short u2 = x[(size_t)__float_as_int(p2.x) * ED + lane];
        unsigned short u3 = x[(size_t)__float_as_int(p3.x) * ED + lane];
        a += p0.y * b2f(u0); a += p1.y * b2f(u1);
        a += p2.y * b2f(u2); a += p3.y * b2f(u3);
    }
    for (; j < end; ++j) {
        float2 p = ldnt(csr + j);
        a += p.y * b2f(x[(size_t)__float_as_int(p.x) * ED + lane]);
    }
    if (ACC) {
        size_t o = (size_t)nid * ED + lane;
        acc[o] += attn[3] * a;
    } else {
        y[(size_t)nid * ED + lane] = f2b(a);
    }
}

// out0 = emb ; acc = a0*emb + a1*y1 + a2*y2
__global__ void k_combine3(const float* __restrict__ emb, const unsigned short* __restrict__ y1,
                           const unsigned short* __restrict__ y2, const float* __restrict__ attn,
                           float* __restrict__ out0, float* __restrict__ acc) {
    int i = blockIdx.x * 256 + threadIdx.x;    // float4 index, 6250 blocks exact
    float4 e = reinterpret_cast<const float4*>(emb)[i];
    ushort4 a1 = reinterpret_cast<const ushort4*>(y1)[i];
    ushort4 a2 = reinterpret_cast<const ushort4*>(y2)[i];
    float w0 = attn[0], w1 = attn[1], w2 = attn[2];
    float4 r;
    r.x = w0 * e.x + w1 * b2f(a1.x) + w2 * b2f(a2.x);
    r.y = w0 * e.y + w1 * b2f(a1.y) + w2 * b2f(a2.y);
    r.z = w0 * e.z + w1 * b2f(a1.z) + w2 * b2f(a2.z);
    r.w = w0 * e.w + w1 * b2f(a1.w) + w2 * b2f(a2.w);
    reinterpret_cast<float4*>(out0)[i] = e;
    reinterpret_cast<float4*>(acc)[i] = r;
}

extern "C" void kernel_launch(void* const* d_in, const int* in_sizes, int n_in,
                              void* d_out, int out_size, void* d_ws, size_t ws_size,
                              hipStream_t stream) {
    const float* emb   = (const float*)d_in[0];
    const float* attw  = (const float*)d_in[1];
    const float* scale = (const float*)d_in[2];
    const float* attr  = (const float*)d_in[3];
    const int*   ei    = (const int*)d_in[4];
    const int* src = ei;
    const int* dst = ei + NE;

    float* out0 = (float*)d_out;
    float* acc  = out0 + (size_t)NN * ED;

    // workspace (~65 MB): part (25.6M) is dead after k_place -> aliased by x0,y1
    char* ws = (char*)d_ws;
    size_t off = 0;
    float*  attn   = (float*)(ws + off);  off += 256;
    int*    degi   = (int*)(ws + off);    off += ((size_t)NN * 4 + 255) & ~(size_t)255;
    int*    rowptr = (int*)(ws + off);    off += ((size_t)NN * 4 + 255) & ~(size_t)255;
    int*    bsum   = (int*)(ws + off);    off += 512;
    int*    gcur   = (int*)(ws + off);    off += 1024;
    unsigned long long* part = (unsigned long long*)(ws + off); off += (size_t)NE * 8;
    float2* csr    = (float2*)(ws + off); off += (size_t)NE * 8;
    unsigned short* y2 = (unsigned short*)(ws + off); off += (size_t)NN * ED * 2;
    unsigned short* x0 = (unsigned short*)part;                       // alias (dead part)
    unsigned short* y1 = (unsigned short*)part + (size_t)NN * ED;     // alias

    const int NB = (NN + 255) / 256;       // 391
    const int VB = (NN * ED / 4) / 256;    // 6250 exact
    const int GB = (NN * ED) / 256;        // 25000 exact
    const int CB = (NE / 4) / 256;         // 3125 exact
    const int PB = (NE + CHUNK - 1) / CHUNK; // 391

    hipMemsetAsync(degi, 0, (size_t)NN * 4, stream);
    k_softmax<<<1, 1, 0, stream>>>(attw, attn);
    k_count<<<CB, 256, 0, stream>>>(dst, degi);
    k_scan1<<<SCAN_BLOCKS, 1024, 0, stream>>>(degi, rowptr, bsum);
    k_scan2<<<1, 64, 0, stream>>>(bsum);
    k_scan3<<<SCAN_BLOCKS, 1024, 0, stream>>>(rowptr, bsum);
    k_dinv<<<NB, 256, 0, stream>>>(degi);
    k_bcur<<<1, 256, 0, stream>>>(rowptr, gcur);
    k_part<<<PB, PTH, 0, stream>>>(src, dst, attr, scale, (const float*)degi, gcur, part);
    k_place<<<NBUCK, 512, 0, stream>>>(rowptr, part, csr);

    k_prep<<<VB, 256, 0, stream>>>(emb, x0);   // part is dead now; x0/y1 alias it

    k_gather<false><<<GB, 256, 0, stream>>>(rowptr, csr, x0, y1, nullptr, attn);
    k_gather<false><<<GB, 256, 0, stream>>>(rowptr, csr, y1, y2, nullptr, attn);
    k_combine3<<<VB, 256, 0, stream>>>(emb, y1, y2, attn, out0, acc);
    k_gather<true><<<GB, 256, 0, stream>>>(rowptr, csr, y2, nullptr, acc, attn);
}

// Round 5
// 488.487 us; speedup vs baseline: 17.0297x; 1.3342x over previous
//
#include <hip/hip_runtime.h>
#include <hip/hip_fp16.h>

#define NN 100000          // N_NODES
#define ED 64              // EMB_DIM
#define NE 3200000         // N_EDGES
#define SCAN_BLOCKS ((NN + 1023) / 1024)   // 98
#define BSH 9                              // log2 nodes per bucket
#define BNODES 512
#define NBUCK ((NN + BNODES - 1) / BNODES) // 196
#define CHUNK 8192
#define PTH 512

__device__ __forceinline__ float b2f(unsigned short u) {
    return __uint_as_float(((unsigned)u) << 16);
}
__device__ __forceinline__ unsigned short f2b(float f) {
    unsigned x = __float_as_uint(f);
    return (unsigned short)((x + 0x7FFFu + ((x >> 16) & 1u)) >> 16);  // RNE
}

__global__ void k_softmax(const float* __restrict__ w, float* __restrict__ attn) {
    float m = fmaxf(fmaxf(w[0], w[1]), fmaxf(w[2], w[3]));
    float e0 = expf(w[0] - m), e1 = expf(w[1] - m), e2 = expf(w[2] - m), e3 = expf(w[3] - m);
    float s = e0 + e1 + e2 + e3;
    attn[0] = e0 / s; attn[1] = e1 / s; attn[2] = e2 / s; attn[3] = e3 / s;
}

// per-node degree histogram, int4 vectorized. grid = NE/4/256 = 3125 exact
__global__ void k_count(const int* __restrict__ dst, int* __restrict__ degi) {
    int i = blockIdx.x * 256 + threadIdx.x;
    int4 d = reinterpret_cast<const int4*>(dst)[i];
    atomicAdd(&degi[d.x], 1); atomicAdd(&degi[d.y], 1);
    atomicAdd(&degi[d.z], 1); atomicAdd(&degi[d.w], 1);
}

// phase 1: per-block exclusive scan + block sums; also dinvf = rsqrt(deg)
__global__ void k_scan1(const int* __restrict__ degi, int* __restrict__ rowptr,
                        int* __restrict__ bsum, float* __restrict__ dinvf) {
    __shared__ int wsum[16];
    const int tid = threadIdx.x, lane = tid & 63, wv = tid >> 6;
    int i = blockIdx.x * 1024 + tid;
    int v = (i < NN) ? degi[i] : 0;
    int x = v;
    #pragma unroll
    for (int o = 1; o < 64; o <<= 1) { int t = __shfl_up(x, o, 64); if (lane >= o) x += t; }
    if (lane == 63) wsum[wv] = x;
    __syncthreads();
    if (tid < 16) {
        int orig = wsum[tid]; int t = orig;
        #pragma unroll
        for (int o = 1; o < 16; o <<= 1) { int u = __shfl_up(t, o, 64); if (tid >= o) t += u; }
        wsum[tid] = t - orig;
        if (tid == 15) bsum[blockIdx.x] = t;
    }
    __syncthreads();
    if (i < NN) {
        rowptr[i] = wsum[wv] + (x - v);
        dinvf[i] = (v > 0) ? rsqrtf((float)v) : 0.0f;
    }
}

__global__ void k_scan2(int* __restrict__ bsum) {
    int lane = threadIdx.x;  // 64 threads
    int v0 = (lane < SCAN_BLOCKS) ? bsum[lane] : 0;
    int v1 = (64 + lane < SCAN_BLOCKS) ? bsum[64 + lane] : 0;
    int s0 = v0;
    #pragma unroll
    for (int o = 1; o < 64; o <<= 1) { int t = __shfl_up(s0, o, 64); if (lane >= o) s0 += t; }
    int tot0 = __shfl(s0, 63, 64);
    int s1 = v1;
    #pragma unroll
    for (int o = 1; o < 64; o <<= 1) { int t = __shfl_up(s1, o, 64); if (lane >= o) s1 += t; }
    if (lane < SCAN_BLOCKS) bsum[lane] = s0 - v0;
    if (64 + lane < SCAN_BLOCKS) bsum[64 + lane] = tot0 + s1 - v1;
}

// phase 3: add block offsets; also emit bucket-start cursors
__global__ void k_scan3(int* __restrict__ rowptr, const int* __restrict__ bsum,
                        int* __restrict__ gcur) {
    int i = blockIdx.x * 1024 + threadIdx.x;
    if (i < NN) {
        int r = rowptr[i] + bsum[blockIdx.x];
        rowptr[i] = r;
        if ((i & (BNODES - 1)) == 0) gcur[i >> BSH] = r;
    }
}

// pass 1: partition edges into dst-buckets with LDS staging + coalesced flush.
// entry u64 = (coef f32) << 32 | (dst_local 9b) << 17 | (src 17b)
__global__ void __launch_bounds__(PTH) k_part(const int* __restrict__ src,
        const int* __restrict__ dst, const float* __restrict__ attr,
        const float* __restrict__ scale, const float* __restrict__ dinv,
        int* __restrict__ gcur, unsigned long long* __restrict__ part) {
    __shared__ unsigned long long stage[CHUNK];   // 64 KiB
    __shared__ int hist[NBUCK];
    __shared__ int lstart[NBUCK + 1];
    __shared__ int gbase[NBUCK];
    __shared__ unsigned char bkof[CHUNK];         // 8 KiB
    const int tid = threadIdx.x;
    const int base = blockIdx.x * CHUNK;
    const int n = min(CHUNK, NE - base);
    for (int i = tid; i < NBUCK; i += PTH) hist[i] = 0;
    __syncthreads();
    for (int i = tid; i < n; i += PTH) atomicAdd(&hist[dst[base + i] >> BSH], 1);
    __syncthreads();
    if (tid < 64) {                                // exclusive scan of hist
        int carry = 0;
        #pragma unroll
        for (int g = 0; g < 4; ++g) {
            int b = g * 64 + tid;
            int v = (b < NBUCK) ? hist[b] : 0;
            int s = v;
            #pragma unroll
            for (int o = 1; o < 64; o <<= 1) { int t = __shfl_up(s, o, 64); if (tid >= o) s += t; }
            if (b < NBUCK) lstart[b] = carry + s - v;
            carry += __shfl(s, 63, 64);
        }
        if (tid == 0) lstart[NBUCK] = n;
    }
    __syncthreads();
    for (int b = tid; b < NBUCK; b += PTH) {
        int cnt = lstart[b + 1] - lstart[b];
        gbase[b] = atomicAdd(&gcur[b], cnt);
        hist[b] = lstart[b];
    }
    __syncthreads();
    float sc = scale[0];
    for (int i = tid; i < n; i += PTH) {
        int e = base + i;
        int s = src[e], d = dst[e];
        float c = dinv[s] * dinv[d] * expf(sc * attr[e]);
        int bk = d >> BSH;
        int p = atomicAdd(&hist[bk], 1);
        stage[p] = ((unsigned long long)__float_as_uint(c) << 32)
                 | (unsigned)(s | ((d & (BNODES - 1)) << 17));
        bkof[p] = (unsigned char)bk;
    }
    __syncthreads();
    for (int i = tid; i < n; i += PTH) {
        int bk = bkof[i];
        part[(size_t)gbase[bk] + (i - lstart[bk])] = stage[i];
    }
}

// pass 2: per-bucket exact placement into split arrays es (int32) + ew (fp16)
__global__ void __launch_bounds__(512) k_place(const int* __restrict__ rowptr,
        const unsigned long long* __restrict__ part,
        int* __restrict__ es, __half* __restrict__ ew) {
    __shared__ int cur[BNODES];
    const int b = blockIdx.x;
    const int node0 = b * BNODES;
    const int tid = threadIdx.x;
    int node = node0 + tid;
    cur[tid] = (node < NN) ? rowptr[node] : 0;
    const int rs = rowptr[node0];
    const int re = (node0 + BNODES < NN) ? rowptr[node0 + BNODES] : NE;
    __syncthreads();
    for (int j = rs + tid; j < re; j += 512) {
        unsigned long long v = part[j];
        unsigned lo = (unsigned)v;
        int s  = lo & 0x1FFFF;
        int dl = (lo >> 17) & (BNODES - 1);
        float c = __uint_as_float((unsigned)(v >> 32));
        int p = atomicAdd(&cur[dl], 1);
        es[p] = s;
        ew[p] = __float2half(c);
    }
}

// x0 = bf16(emb). grid = NN*ED/4/256 = 6250 exact
__global__ void k_prep(const float* __restrict__ emb, unsigned short* __restrict__ x0) {
    int i = blockIdx.x * 256 + threadIdx.x;
    float4 e = reinterpret_cast<const float4*>(emb)[i];
    ushort4 u;
    u.x = f2b(e.x); u.y = f2b(e.y); u.z = f2b(e.z); u.w = f2b(e.w);
    reinterpret_cast<ushort4*>(x0)[i] = u;
}

// gather: one wave per node, lane owns one dim. Edge metadata through
// scalar path (beg/end forced to SGPR), x loads own the vmcnt queue.
template <bool ACC>
__global__ void __launch_bounds__(256) k_gather(const int* __restrict__ rowptr,
        const int* __restrict__ es, const __half* __restrict__ ew,
        const unsigned short* __restrict__ x,
        unsigned short* __restrict__ y, float* __restrict__ acc,
        const float* __restrict__ attn) {
    int gt = blockIdx.x * 256 + threadIdx.x;   // grid = NN*64/256 = 25000 exact
    int nid = gt >> 6;                         // wave-uniform
    int lane = gt & 63;
    int beg = __builtin_amdgcn_readfirstlane(rowptr[nid]);
    int end = __builtin_amdgcn_readfirstlane((nid < NN - 1) ? rowptr[nid + 1] : NE);
    float a = 0.0f;
    int j = beg;
    for (; j + 8 <= end; j += 8) {
        float xv[8];
        #pragma unroll
        for (int k = 0; k < 8; ++k) {
            int s = es[j + k];                 // uniform -> scalar load
            xv[k] = b2f(x[(size_t)s * ED + lane]);
        }
        #pragma unroll
        for (int k = 0; k < 8; ++k) {
            a += __half2float(ew[j + k]) * xv[k];
        }
    }
    for (; j < end; ++j) {
        int s = es[j];
        a += __half2float(ew[j]) * b2f(x[(size_t)s * ED + lane]);
    }
    if (ACC) {
        size_t o = (size_t)nid * ED + lane;
        acc[o] += attn[3] * a;
    } else {
        y[(size_t)nid * ED + lane] = f2b(a);
    }
}

// out0 = emb ; acc = a0*emb + a1*y1 + a2*y2
__global__ void k_combine3(const float* __restrict__ emb, const unsigned short* __restrict__ y1,
                           const unsigned short* __restrict__ y2, const float* __restrict__ attn,
                           float* __restrict__ out0, float* __restrict__ acc) {
    int i = blockIdx.x * 256 + threadIdx.x;    // float4 index, 6250 blocks exact
    float4 e = reinterpret_cast<const float4*>(emb)[i];
    ushort4 a1 = reinterpret_cast<const ushort4*>(y1)[i];
    ushort4 a2 = reinterpret_cast<const ushort4*>(y2)[i];
    float w0 = attn[0], w1 = attn[1], w2 = attn[2];
    float4 r;
    r.x = w0 * e.x + w1 * b2f(a1.x) + w2 * b2f(a2.x);
    r.y = w0 * e.y + w1 * b2f(a1.y) + w2 * b2f(a2.y);
    r.z = w0 * e.z + w1 * b2f(a1.z) + w2 * b2f(a2.z);
    r.w = w0 * e.w + w1 * b2f(a1.w) + w2 * b2f(a2.w);
    reinterpret_cast<float4*>(out0)[i] = e;
    reinterpret_cast<float4*>(acc)[i] = r;
}

extern "C" void kernel_launch(void* const* d_in, const int* in_sizes, int n_in,
                              void* d_out, int out_size, void* d_ws, size_t ws_size,
                              hipStream_t stream) {
    const float* emb   = (const float*)d_in[0];
    const float* attw  = (const float*)d_in[1];
    const float* scale = (const float*)d_in[2];
    const float* attr  = (const float*)d_in[3];
    const int*   ei    = (const int*)d_in[4];
    const int* src = ei;
    const int* dst = ei + NE;

    float* out0 = (float*)d_out;
    float* acc  = out0 + (size_t)NN * ED;

    // workspace (~59 MB): part (25.6MB) dead after k_place -> aliased by x0,y1
    char* ws = (char*)d_ws;
    size_t off = 0;
    float*  attn   = (float*)(ws + off);  off += 256;
    int*    degi   = (int*)(ws + off);    off += ((size_t)NN * 4 + 255) & ~(size_t)255;
    float*  dinvf  = (float*)(ws + off);  off += ((size_t)NN * 4 + 255) & ~(size_t)255;
    int*    rowptr = (int*)(ws + off);    off += ((size_t)NN * 4 + 255) & ~(size_t)255;
    int*    bsum   = (int*)(ws + off);    off += 512;
    int*    gcur   = (int*)(ws + off);    off += 1024;
    unsigned long long* part = (unsigned long long*)(ws + off); off += (size_t)NE * 8;
    int*    es     = (int*)(ws + off);    off += (size_t)NE * 4;
    __half* ew     = (__half*)(ws + off); off += (size_t)NE * 2;
    unsigned short* y2 = (unsigned short*)(ws + off); off += (size_t)NN * ED * 2;
    unsigned short* x0 = (unsigned short*)part;                       // alias (dead part)
    unsigned short* y1 = (unsigned short*)part + (size_t)NN * ED;     // alias

    const int VB = (NN * ED / 4) / 256;    // 6250 exact
    const int GB = (NN * ED) / 256;        // 25000 exact
    const int CB = (NE / 4) / 256;         // 3125 exact
    const int PB = (NE + CHUNK - 1) / CHUNK; // 391

    hipMemsetAsync(degi, 0, (size_t)NN * 4, stream);
    k_softmax<<<1, 1, 0, stream>>>(attw, attn);
    k_count<<<CB, 256, 0, stream>>>(dst, degi);
    k_scan1<<<SCAN_BLOCKS, 1024, 0, stream>>>(degi, rowptr, bsum, dinvf);
    k_scan2<<<1, 64, 0, stream>>>(bsum);
    k_scan3<<<SCAN_BLOCKS, 1024, 0, stream>>>(rowptr, bsum, gcur);
    k_part<<<PB, PTH, 0, stream>>>(src, dst, attr, scale, dinvf, gcur, part);
    k_place<<<NBUCK, 512, 0, stream>>>(rowptr, part, es, ew);

    k_prep<<<VB, 256, 0, stream>>>(emb, x0);   // part dead now; x0/y1 alias it

    k_gather<false><<<GB, 256, 0, stream>>>(rowptr, es, ew, x0, y1, nullptr, attn);
    k_gather<false><<<GB, 256, 0, stream>>>(rowptr, es, ew, y1, y2, nullptr, attn);
    k_combine3<<<VB, 256, 0, stream>>>(emb, y1, y2, attn, out0, acc);
    k_gather<true><<<GB, 256, 0, stream>>>(rowptr, es, ew, y2, nullptr, acc, attn);
}

// Round 6
// 331.301 us; speedup vs baseline: 25.1094x; 1.4744x over previous
//
#include <hip/hip_runtime.h>
#include <hip/hip_fp16.h>

#define NN 100000          // N_NODES
#define ED 64              // EMB_DIM
#define NE 3200000         // N_EDGES
#define BSH 9              // log2 nodes per bucket
#define BNODES 512
#define NBUCK ((NN + BNODES - 1) / BNODES) // 196
#define CHUNK 8192
#define PTH 512

__device__ __forceinline__ float b2f(unsigned short u) {
    return __uint_as_float(((unsigned)u) << 16);
}
__device__ __forceinline__ unsigned short f2b(float f) {
    unsigned x = __float_as_uint(f);
    return (unsigned short)((x + 0x7FFFu + ((x >> 16) & 1u)) >> 16);  // RNE
}

__global__ void k_softmax(const float* __restrict__ w, float* __restrict__ attn) {
    float m = fmaxf(fmaxf(w[0], w[1]), fmaxf(w[2], w[3]));
    float e0 = expf(w[0] - m), e1 = expf(w[1] - m), e2 = expf(w[2] - m), e3 = expf(w[3] - m);
    float s = e0 + e1 + e2 + e3;
    attn[0] = e0 / s; attn[1] = e1 / s; attn[2] = e2 / s; attn[3] = e3 / s;
}

// bucket histogram: LDS-privatized, one global flush per block (196*391 atomics)
__global__ void __launch_bounds__(256) k_bcount(const int* __restrict__ dst,
                                                int* __restrict__ bcnt) {
    __shared__ int h[NBUCK];
    const int tid = threadIdx.x;
    for (int i = tid; i < NBUCK; i += 256) h[i] = 0;
    __syncthreads();
    int i0 = blockIdx.x * 2048;                 // int4 units (8192 edges/block)
    int i1 = min(i0 + 2048, NE / 4);
    for (int i = i0 + tid; i < i1; i += 256) {
        int4 d = reinterpret_cast<const int4*>(dst)[i];
        atomicAdd(&h[d.x >> BSH], 1); atomicAdd(&h[d.y >> BSH], 1);
        atomicAdd(&h[d.z >> BSH], 1); atomicAdd(&h[d.w >> BSH], 1);
    }
    __syncthreads();
    for (int i = tid; i < NBUCK; i += 256) if (h[i]) atomicAdd(&bcnt[i], h[i]);
}

// exclusive scan of bcnt[NBUCK] -> bstart (kept) and gcur (mutated by k_part)
__global__ void k_bscan(const int* __restrict__ bcnt, int* __restrict__ bstart,
                        int* __restrict__ gcur) {
    int tid = threadIdx.x;  // 64
    int carry = 0;
    #pragma unroll
    for (int g = 0; g < 4; ++g) {
        int b = g * 64 + tid;
        int v = (b < NBUCK) ? bcnt[b] : 0;
        int s = v;
        #pragma unroll
        for (int o = 1; o < 64; o <<= 1) { int t = __shfl_up(s, o, 64); if (tid >= o) s += t; }
        if (b < NBUCK) { int e = carry + s - v; bstart[b] = e; gcur[b] = e; }
        carry += __shfl(s, 63, 64);
    }
    if (tid == 0) bstart[NBUCK] = NE;
}

// pass 1: partition edges into dst-buckets. entry = attr f32 <<32 | dl 9b <<17 | src 17b
__global__ void __launch_bounds__(PTH) k_part(const int* __restrict__ src,
        const int* __restrict__ dst, const float* __restrict__ attr,
        int* __restrict__ gcur, unsigned long long* __restrict__ part) {
    __shared__ unsigned long long stage[CHUNK];   // 64 KiB
    __shared__ int hist[NBUCK];
    __shared__ int lstart[NBUCK + 1];
    __shared__ int gbase[NBUCK];
    __shared__ unsigned char bkof[CHUNK];         // 8 KiB
    const int tid = threadIdx.x;
    const int base = blockIdx.x * CHUNK;
    const int n = min(CHUNK, NE - base);
    for (int i = tid; i < NBUCK; i += PTH) hist[i] = 0;
    __syncthreads();
    for (int i = tid; i < n; i += PTH) atomicAdd(&hist[dst[base + i] >> BSH], 1);
    __syncthreads();
    if (tid < 64) {                                // exclusive scan of hist
        int carry = 0;
        #pragma unroll
        for (int g = 0; g < 4; ++g) {
            int b = g * 64 + tid;
            int v = (b < NBUCK) ? hist[b] : 0;
            int s = v;
            #pragma unroll
            for (int o = 1; o < 64; o <<= 1) { int t = __shfl_up(s, o, 64); if (tid >= o) s += t; }
            if (b < NBUCK) lstart[b] = carry + s - v;
            carry += __shfl(s, 63, 64);
        }
        if (tid == 0) lstart[NBUCK] = n;
    }
    __syncthreads();
    for (int b = tid; b < NBUCK; b += PTH) {
        int cnt = lstart[b + 1] - lstart[b];
        gbase[b] = atomicAdd(&gcur[b], cnt);
        hist[b] = lstart[b];
    }
    __syncthreads();
    for (int i = tid; i < n; i += PTH) {
        int e = base + i;
        int s = src[e], d = dst[e];
        int bk = d >> BSH;
        int p = atomicAdd(&hist[bk], 1);
        stage[p] = ((unsigned long long)__float_as_uint(attr[e]) << 32)
                 | (unsigned)(s | ((d & (BNODES - 1)) << 17));
        bkof[p] = (unsigned char)bk;
    }
    __syncthreads();
    for (int i = tid; i < n; i += PTH) {
        int bk = bkof[i];
        part[(size_t)gbase[bk] + (i - lstart[bk])] = stage[i];
    }
}

// per-bucket degree count (LDS only) + block scan -> rowptr, dinvf. No global atomics.
__global__ void __launch_bounds__(512) k_ndeg(const int* __restrict__ bstart,
        const unsigned long long* __restrict__ part,
        int* __restrict__ rowptr, float* __restrict__ dinvf) {
    __shared__ int h[BNODES];
    __shared__ int wsum[8];
    const int b = blockIdx.x, tid = threadIdx.x;
    const int lane = tid & 63, wv = tid >> 6;
    h[tid] = 0;
    __syncthreads();
    const int rs = bstart[b], re = bstart[b + 1];
    for (int j = rs + tid; j < re; j += 512) {
        unsigned lo = (unsigned)part[j];
        atomicAdd(&h[(lo >> 17) & (BNODES - 1)], 1);
    }
    __syncthreads();
    int v = h[tid];
    int x = v;
    #pragma unroll
    for (int o = 1; o < 64; o <<= 1) { int t = __shfl_up(x, o, 64); if (lane >= o) x += t; }
    if (lane == 63) wsum[wv] = x;
    __syncthreads();
    if (tid < 8) {
        int orig = wsum[tid]; int t = orig;
        #pragma unroll
        for (int o = 1; o < 8; o <<= 1) { int u = __shfl_up(t, o, 64); if (tid >= o) t += u; }
        wsum[tid] = t - orig;
    }
    __syncthreads();
    int node = b * BNODES + tid;
    if (node < NN) {
        rowptr[node] = rs + wsum[wv] + (x - v);
        dinvf[node] = (v > 0) ? rsqrtf((float)v) : 0.0f;
    }
}

// pass 2: per-bucket coef compute + exact placement into es (int32) + ew (fp16)
__global__ void __launch_bounds__(512) k_place(const int* __restrict__ bstart,
        const int* __restrict__ rowptr, const unsigned long long* __restrict__ part,
        const float* __restrict__ dinvf, const float* __restrict__ scale,
        int* __restrict__ es, __half* __restrict__ ew) {
    __shared__ int cur[BNODES];
    __shared__ float dli[BNODES];
    const int b = blockIdx.x, tid = threadIdx.x;
    int node = b * BNODES + tid;
    cur[tid] = (node < NN) ? rowptr[node] : 0;
    dli[tid] = (node < NN) ? dinvf[node] : 0.0f;
    __syncthreads();
    const int rs = bstart[b], re = bstart[b + 1];
    const float sc = scale[0];
    for (int j = rs + tid; j < re; j += 512) {
        unsigned long long v = part[j];
        unsigned lo = (unsigned)v;
        int s  = lo & 0x1FFFF;
        int dl = (lo >> 17) & (BNODES - 1);
        float at = __uint_as_float((unsigned)(v >> 32));
        float c = dinvf[s] * dli[dl] * expf(sc * at);
        int p = atomicAdd(&cur[dl], 1);
        es[p] = s;
        ew[p] = __float2half(c);
    }
}

// x0 = bf16(emb). grid = NN*ED/4/256 = 6250 exact
__global__ void k_prep(const float* __restrict__ emb, unsigned short* __restrict__ x0) {
    int i = blockIdx.x * 256 + threadIdx.x;
    float4 e = reinterpret_cast<const float4*>(emb)[i];
    ushort4 u;
    u.x = f2b(e.x); u.y = f2b(e.y); u.z = f2b(e.z); u.w = f2b(e.w);
    reinterpret_cast<ushort4*>(x0)[i] = u;
}

// gather: one wave per node; lanes 0-31 even edges, 32-63 odd edges;
// each lane loads a ushort2 dim-pair (4B). Edge metadata via scalar loads.
__global__ void __launch_bounds__(256) k_gather(const int* __restrict__ rowptr,
        const int* __restrict__ es, const __half* __restrict__ ew,
        const unsigned short* __restrict__ x, unsigned short* __restrict__ y) {
    int gt = blockIdx.x * 256 + threadIdx.x;   // grid = NN*64/256 = 25000 exact
    int nid = gt >> 6;                         // wave-uniform
    int lane = gt & 63;
    int hi = lane >> 5;                        // 0: even edge, 1: odd edge
    int dim2 = (lane & 31) * 2;
    int beg = __builtin_amdgcn_readfirstlane(rowptr[nid]);
    int end = __builtin_amdgcn_readfirstlane((nid < NN - 1) ? rowptr[nid + 1] : NE);
    float a0 = 0.0f, a1 = 0.0f;
    int j = beg;
    for (; j + 8 <= end; j += 8) {
        #pragma unroll
        for (int k = 0; k < 4; ++k) {
            int s0 = es[j + 2 * k];
            int s1 = es[j + 2 * k + 1];
            float w0 = __half2float(ew[j + 2 * k]);
            float w1 = __half2float(ew[j + 2 * k + 1]);
            int s = hi ? s1 : s0;
            float w = hi ? w1 : w0;
            unsigned u = *reinterpret_cast<const unsigned*>(x + (size_t)s * ED + dim2);
            a0 += w * __uint_as_float(u << 16);
            a1 += w * __uint_as_float(u & 0xFFFF0000u);
        }
    }
    for (; j + 2 <= end; j += 2) {
        int s0 = es[j], s1 = es[j + 1];
        float w0 = __half2float(ew[j]), w1 = __half2float(ew[j + 1]);
        int s = hi ? s1 : s0;
        float w = hi ? w1 : w0;
        unsigned u = *reinterpret_cast<const unsigned*>(x + (size_t)s * ED + dim2);
        a0 += w * __uint_as_float(u << 16);
        a1 += w * __uint_as_float(u & 0xFFFF0000u);
    }
    if (j < end) {                              // odd tail: hi half contributes 0
        int s0 = es[j];
        float w = hi ? 0.0f : __half2float(ew[j]);
        unsigned u = *reinterpret_cast<const unsigned*>(x + (size_t)s0 * ED + dim2);
        a0 += w * __uint_as_float(u << 16);
        a1 += w * __uint_as_float(u & 0xFFFF0000u);
    }
    a0 += __shfl_xor(a0, 32, 64);
    a1 += __shfl_xor(a1, 32, 64);
    if (lane < 32) {
        unsigned o = (unsigned)f2b(a0) | ((unsigned)f2b(a1) << 16);
        *reinterpret_cast<unsigned*>(y + (size_t)nid * ED + dim2) = o;
    }
}

// out0 = emb ; acc = a0*emb + a1*y1 + a2*y2 + a3*y3
__global__ void k_combine4(const float* __restrict__ emb,
                           const unsigned short* __restrict__ y1,
                           const unsigned short* __restrict__ y2,
                           const unsigned short* __restrict__ y3,
                           const float* __restrict__ attn,
                           float* __restrict__ out0, float* __restrict__ acc) {
    int i = blockIdx.x * 256 + threadIdx.x;    // float4 index, 6250 blocks exact
    float4 e = reinterpret_cast<const float4*>(emb)[i];
    ushort4 u1 = reinterpret_cast<const ushort4*>(y1)[i];
    ushort4 u2 = reinterpret_cast<const ushort4*>(y2)[i];
    ushort4 u3 = reinterpret_cast<const ushort4*>(y3)[i];
    float w0 = attn[0], w1 = attn[1], w2 = attn[2], w3 = attn[3];
    float4 r;
    r.x = w0 * e.x + w1 * b2f(u1.x) + w2 * b2f(u2.x) + w3 * b2f(u3.x);
    r.y = w0 * e.y + w1 * b2f(u1.y) + w2 * b2f(u2.y) + w3 * b2f(u3.y);
    r.z = w0 * e.z + w1 * b2f(u1.z) + w2 * b2f(u2.z) + w3 * b2f(u3.z);
    r.w = w0 * e.w + w1 * b2f(u1.w) + w2 * b2f(u2.w) + w3 * b2f(u3.w);
    reinterpret_cast<float4*>(out0)[i] = e;
    reinterpret_cast<float4*>(acc)[i] = r;
}

extern "C" void kernel_launch(void* const* d_in, const int* in_sizes, int n_in,
                              void* d_out, int out_size, void* d_ws, size_t ws_size,
                              hipStream_t stream) {
    const float* emb   = (const float*)d_in[0];
    const float* attw  = (const float*)d_in[1];
    const float* scale = (const float*)d_in[2];
    const float* attr  = (const float*)d_in[3];
    const int*   ei    = (const int*)d_in[4];
    const int* src = ei;
    const int* dst = ei + NE;

    float* out0 = (float*)d_out;
    float* acc  = out0 + (size_t)NN * ED;

    // workspace (~58.5 MB). part dead after k_place -> aliased by x0,y1; x0 dead
    // after gather1 -> aliased by y3.
    char* ws = (char*)d_ws;
    size_t off = 0;
    float*  attn   = (float*)(ws + off);  off += 256;
    int*    bcnt   = (int*)(ws + off);    off += 1024;
    int*    bstart = (int*)(ws + off);    off += 1024;
    int*    gcur   = (int*)(ws + off);    off += 1024;
    float*  dinvf  = (float*)(ws + off);  off += ((size_t)NN * 4 + 255) & ~(size_t)255;
    int*    rowptr = (int*)(ws + off);    off += ((size_t)NN * 4 + 255) & ~(size_t)255;
    unsigned long long* part = (unsigned long long*)(ws + off); off += (size_t)NE * 8;
    int*    es     = (int*)(ws + off);    off += (size_t)NE * 4;
    __half* ew     = (__half*)(ws + off); off += (size_t)NE * 2;
    unsigned short* y2 = (unsigned short*)(ws + off); off += (size_t)NN * ED * 2;
    unsigned short* x0 = (unsigned short*)part;                     // alias
    unsigned short* y1 = (unsigned short*)part + (size_t)NN * ED;   // alias
    unsigned short* y3 = x0;                                        // alias (x0 dead after g1)

    const int VB = (NN * ED / 4) / 256;      // 6250 exact
    const int GB = (NN * ED) / 256;          // 25000 exact
    const int HB = (NE / 4 + 2047) / 2048;   // 391
    const int PB = (NE + CHUNK - 1) / CHUNK; // 391

    hipMemsetAsync(bcnt, 0, NBUCK * 4, stream);
    k_softmax<<<1, 1, 0, stream>>>(attw, attn);
    k_bcount<<<HB, 256, 0, stream>>>(dst, bcnt);
    k_bscan<<<1, 64, 0, stream>>>(bcnt, bstart, gcur);
    k_part<<<PB, PTH, 0, stream>>>(src, dst, attr, gcur, part);
    k_ndeg<<<NBUCK, 512, 0, stream>>>(bstart, part, rowptr, dinvf);
    k_place<<<NBUCK, 512, 0, stream>>>(bstart, rowptr, part, dinvf, scale, es, ew);

    k_prep<<<VB, 256, 0, stream>>>(emb, x0);

    k_gather<<<GB, 256, 0, stream>>>(rowptr, es, ew, x0, y1);
    k_gather<<<GB, 256, 0, stream>>>(rowptr, es, ew, y1, y2);
    k_gather<<<GB, 256, 0, stream>>>(rowptr, es, ew, y2, y3);
    k_combine4<<<VB, 256, 0, stream>>>(emb, y1, y2, y3, attn, out0, acc);
}

// Round 7
// 301.055 us; speedup vs baseline: 27.6322x; 1.1005x over previous
//
#include <hip/hip_runtime.h>
#include <hip/hip_fp16.h>

#define NN 100000          // N_NODES
#define ED 64              // EMB_DIM
#define NE 3200000         // N_EDGES
#define BSH 9              // log2 nodes per bucket
#define BNODES 512
#define NBUCK ((NN + BNODES - 1) / BNODES) // 196
#define CHUNK 8192
#define PTH 512
#define NEP (NE + 8 * NN)  // padded edge capacity (<= 7*NN pad needed)

union U32H2 { unsigned u; __half2 h; };
__device__ __forceinline__ float h2lo(unsigned u) { U32H2 c; c.u = u; return __low2float(c.h); }
__device__ __forceinline__ float h2hi(unsigned u) { U32H2 c; c.u = u; return __high2float(c.h); }

__global__ void k_softmax(const float* __restrict__ w, float* __restrict__ attn) {
    float m = fmaxf(fmaxf(w[0], w[1]), fmaxf(w[2], w[3]));
    float e0 = expf(w[0] - m), e1 = expf(w[1] - m), e2 = expf(w[2] - m), e3 = expf(w[3] - m);
    float s = e0 + e1 + e2 + e3;
    attn[0] = e0 / s; attn[1] = e1 / s; attn[2] = e2 / s; attn[3] = e3 / s;
}

// bucket histogram: LDS-privatized, one global flush per block
__global__ void __launch_bounds__(256) k_bcount(const int* __restrict__ dst,
                                                int* __restrict__ bcnt) {
    __shared__ int h[NBUCK];
    const int tid = threadIdx.x;
    for (int i = tid; i < NBUCK; i += 256) h[i] = 0;
    __syncthreads();
    int i0 = blockIdx.x * 2048;                 // int4 units
    int i1 = min(i0 + 2048, NE / 4);
    for (int i = i0 + tid; i < i1; i += 256) {
        int4 d = reinterpret_cast<const int4*>(dst)[i];
        atomicAdd(&h[d.x >> BSH], 1); atomicAdd(&h[d.y >> BSH], 1);
        atomicAdd(&h[d.z >> BSH], 1); atomicAdd(&h[d.w >> BSH], 1);
    }
    __syncthreads();
    for (int i = tid; i < NBUCK; i += 256) if (h[i]) atomicAdd(&bcnt[i], h[i]);
}

// exclusive scan of bcnt -> bstart (kept) and gcur (mutated by k_part)
__global__ void k_bscan(const int* __restrict__ bcnt, int* __restrict__ bstart,
                        int* __restrict__ gcur) {
    int tid = threadIdx.x;  // 64
    int carry = 0;
    #pragma unroll
    for (int g = 0; g < 4; ++g) {
        int b = g * 64 + tid;
        int v = (b < NBUCK) ? bcnt[b] : 0;
        int s = v;
        #pragma unroll
        for (int o = 1; o < 64; o <<= 1) { int t = __shfl_up(s, o, 64); if (tid >= o) s += t; }
        if (b < NBUCK) { int e = carry + s - v; bstart[b] = e; gcur[b] = e; }
        carry += __shfl(s, 63, 64);
    }
    if (tid == 0) bstart[NBUCK] = NE;
}

// pass 1: partition edges into dst-buckets. entry = attr f32 <<32 | dl 9b <<17 | src 17b
__global__ void __launch_bounds__(PTH) k_part(const int* __restrict__ src,
        const int* __restrict__ dst, const float* __restrict__ attr,
        int* __restrict__ gcur, unsigned long long* __restrict__ part) {
    __shared__ unsigned long long stage[CHUNK];   // 64 KiB
    __shared__ int hist[NBUCK];
    __shared__ int lstart[NBUCK + 1];
    __shared__ int gbase[NBUCK];
    __shared__ unsigned char bkof[CHUNK];         // 8 KiB
    const int tid = threadIdx.x;
    const int base = blockIdx.x * CHUNK;
    const int n = min(CHUNK, NE - base);
    for (int i = tid; i < NBUCK; i += PTH) hist[i] = 0;
    __syncthreads();
    for (int i = tid; i < n; i += PTH) atomicAdd(&hist[dst[base + i] >> BSH], 1);
    __syncthreads();
    if (tid < 64) {                                // exclusive scan of hist
        int carry = 0;
        #pragma unroll
        for (int g = 0; g < 4; ++g) {
            int b = g * 64 + tid;
            int v = (b < NBUCK) ? hist[b] : 0;
            int s = v;
            #pragma unroll
            for (int o = 1; o < 64; o <<= 1) { int t = __shfl_up(s, o, 64); if (tid >= o) s += t; }
            if (b < NBUCK) lstart[b] = carry + s - v;
            carry += __shfl(s, 63, 64);
        }
        if (tid == 0) lstart[NBUCK] = n;
    }
    __syncthreads();
    for (int b = tid; b < NBUCK; b += PTH) {
        int cnt = lstart[b + 1] - lstart[b];
        gbase[b] = atomicAdd(&gcur[b], cnt);
        hist[b] = lstart[b];
    }
    __syncthreads();
    for (int i = tid; i < n; i += PTH) {
        int e = base + i;
        int s = src[e], d = dst[e];
        int bk = d >> BSH;
        int p = atomicAdd(&hist[bk], 1);
        stage[p] = ((unsigned long long)__float_as_uint(attr[e]) << 32)
                 | (unsigned)(s | ((d & (BNODES - 1)) << 17));
        bkof[p] = (unsigned char)bk;
    }
    __syncthreads();
    for (int i = tid; i < n; i += PTH) {
        int bk = bkof[i];
        part[(size_t)gbase[bk] + (i - lstart[bk])] = stage[i];
    }
}

// per-bucket degree count + PADDED (mult-8) local scan.
// rowptr[node] <- local padded offset; dinvf[node] <- rsqrt(deg); pbsum[b] <- bucket padded total
__global__ void __launch_bounds__(512) k_ndeg(const int* __restrict__ bstart,
        const unsigned long long* __restrict__ part,
        int* __restrict__ rowptr, float* __restrict__ dinvf, int* __restrict__ pbsum) {
    __shared__ int h[BNODES];
    __shared__ int wsum[8];
    const int b = blockIdx.x, tid = threadIdx.x;
    const int lane = tid & 63, wv = tid >> 6;
    h[tid] = 0;
    __syncthreads();
    const int rs = bstart[b], re = bstart[b + 1];
    for (int j = rs + tid; j < re; j += 512) {
        unsigned lo = (unsigned)part[j];
        atomicAdd(&h[(lo >> 17) & (BNODES - 1)], 1);
    }
    __syncthreads();
    int deg = h[tid];
    int pd = (deg + 7) & ~7;
    int x = pd;
    #pragma unroll
    for (int o = 1; o < 64; o <<= 1) { int t = __shfl_up(x, o, 64); if (lane >= o) x += t; }
    if (lane == 63) wsum[wv] = x;
    __syncthreads();
    if (tid < 8) {
        int orig = wsum[tid]; int t = orig;
        #pragma unroll
        for (int o = 1; o < 8; o <<= 1) { int u = __shfl_up(t, o, 64); if (tid >= o) t += u; }
        wsum[tid] = t - orig;
    }
    __syncthreads();
    int node = b * BNODES + tid;
    int lofs = wsum[wv] + (x - pd);              // exclusive padded offset in bucket
    if (node < NN) {
        rowptr[node] = lofs;
        dinvf[node] = (deg > 0) ? rsqrtf((float)deg) : 0.0f;
    }
    if (tid == 511) pbsum[b] = wsum[7] + x;      // bucket padded total
}

// scan pbsum -> pbase[NBUCK+1]; rowptr[NN] = grand padded total
__global__ void k_pbscan(const int* __restrict__ pbsum, int* __restrict__ pbase,
                         int* __restrict__ rowptr) {
    int tid = threadIdx.x;  // 64
    int carry = 0;
    #pragma unroll
    for (int g = 0; g < 4; ++g) {
        int b = g * 64 + tid;
        int v = (b < NBUCK) ? pbsum[b] : 0;
        int s = v;
        #pragma unroll
        for (int o = 1; o < 64; o <<= 1) { int t = __shfl_up(s, o, 64); if (tid >= o) s += t; }
        if (b < NBUCK) pbase[b] = carry + s - v;
        carry += __shfl(s, 63, 64);
    }
    if (tid == 0) { pbase[NBUCK] = carry; rowptr[NN] = carry; }
}

// pass 2: coef + exact placement into padded slots; zero the pad; finalize rowptr
__global__ void __launch_bounds__(512) k_place(const int* __restrict__ bstart,
        const int* __restrict__ pbase, const int* __restrict__ pbsum,
        const unsigned long long* __restrict__ part,
        const float* __restrict__ dinvf, const float* __restrict__ scale,
        int* __restrict__ es, __half* __restrict__ ew, int* __restrict__ rowptr) {
    __shared__ int cur[BNODES];
    __shared__ int lofs_s[BNODES];
    __shared__ float dli[BNODES];
    const int b = blockIdx.x, tid = threadIdx.x;
    const int node = b * BNODES + tid;
    const int base = pbase[b];
    const int ltot = pbsum[b];
    int lofs = (node < NN) ? rowptr[node] : ltot;
    lofs_s[tid] = lofs;
    cur[tid] = base + lofs;
    dli[tid] = (node < NN) ? dinvf[node] : 0.0f;
    __syncthreads();
    const int rs = bstart[b], re = bstart[b + 1];
    const float sc = scale[0];
    for (int j = rs + tid; j < re; j += 512) {
        unsigned long long v = part[j];
        unsigned lo = (unsigned)v;
        int s  = lo & 0x1FFFF;
        int dl = (lo >> 17) & (BNODES - 1);
        float at = __uint_as_float((unsigned)(v >> 32));
        float c = dinvf[s] * dli[dl] * expf(sc * at);
        int p = atomicAdd(&cur[dl], 1);
        es[p] = s;
        ew[p] = __float2half(c);
    }
    __syncthreads();
    int rowend = base + ((tid == 511) ? ltot : lofs_s[tid + 1]);
    for (int p = cur[tid]; p < rowend; ++p) { es[p] = 0; ew[p] = __float2half(0.0f); }
    if (node < NN) rowptr[node] = base + lofs;   // final padded row start
}

// x0 = fp16(emb). grid = NN*ED/4/256 = 6250 exact
__global__ void k_prep(const float* __restrict__ emb, unsigned short* __restrict__ x0) {
    int i = blockIdx.x * 256 + threadIdx.x;
    float4 e = reinterpret_cast<const float4*>(emb)[i];
    ushort4 u;
    u.x = __half_as_ushort(__float2half(e.x));
    u.y = __half_as_ushort(__float2half(e.y));
    u.z = __half_as_ushort(__float2half(e.z));
    u.w = __half_as_ushort(__float2half(e.w));
    reinterpret_cast<ushort4*>(x0)[i] = u;
}

// gather: one wave per node; 4 lane-groups of 16 handle 4 edges at once;
// each lane loads uint2 = 4 fp16 dims. Rows padded to multiple of 8 edges.
// FINAL: fused epilogue writes out0 = emb and acc = w0*emb+w1*y1+w2*y2+w3*P(y2).
template <bool FINAL>
__global__ void __launch_bounds__(256) k_gather(const int* __restrict__ rowptr,
        const int* __restrict__ es, const __half* __restrict__ ew,
        const unsigned short* __restrict__ x, unsigned short* __restrict__ y,
        const unsigned short* __restrict__ y1, const float* __restrict__ emb,
        const float* __restrict__ attnp, float* __restrict__ out0,
        float* __restrict__ acc) {
    int gt = blockIdx.x * 256 + threadIdx.x;   // grid = NN*64/256 = 25000 exact
    int nid = gt >> 6;                         // wave-uniform
    int lane = gt & 63;
    int g = lane >> 4;                         // edge slot 0..3
    int gi = lane & 15;                        // dword-pair index (4 dims)
    int beg = __builtin_amdgcn_readfirstlane(rowptr[nid]);
    int end = __builtin_amdgcn_readfirstlane(rowptr[nid + 1]);
    const unsigned* ewu = reinterpret_cast<const unsigned*>(ew);
    const uint2* xv = reinterpret_cast<const uint2*>(x);
    float a0 = 0.0f, a1 = 0.0f, a2 = 0.0f, a3 = 0.0f;
    for (int j = beg; j < end; j += 8) {
        #pragma unroll
        for (int k = 0; k < 2; ++k) {
            int jj = j + 4 * k;
            int s0 = es[jj], s1 = es[jj + 1], s2 = es[jj + 2], s3 = es[jj + 3];
            unsigned w01 = ewu[(jj >> 1)], w23 = ewu[(jj >> 1) + 1];
            int sA = (g & 1) ? s1 : s0;
            int sB = (g & 1) ? s3 : s2;
            int s = (g & 2) ? sB : sA;
            unsigned wp = (g & 2) ? w23 : w01;
            float w = (g & 1) ? h2hi(wp) : h2lo(wp);
            uint2 u = xv[(size_t)s * 16 + gi];
            a0 += w * h2lo(u.x); a1 += w * h2hi(u.x);
            a2 += w * h2lo(u.y); a3 += w * h2hi(u.y);
        }
    }
    a0 += __shfl_xor(a0, 16, 64); a0 += __shfl_xor(a0, 32, 64);
    a1 += __shfl_xor(a1, 16, 64); a1 += __shfl_xor(a1, 32, 64);
    a2 += __shfl_xor(a2, 16, 64); a2 += __shfl_xor(a2, 32, 64);
    a3 += __shfl_xor(a3, 16, 64); a3 += __shfl_xor(a3, 32, 64);
    if (lane < 16) {
        size_t ri = (size_t)nid * 16 + gi;     // uint2-granular row slot
        if (!FINAL) {
            U32H2 o01, o23;
            o01.h = __floats2half2_rn(a0, a1);
            o23.h = __floats2half2_rn(a2, a3);
            uint2 o; o.x = o01.u; o.y = o23.u;
            reinterpret_cast<uint2*>(y)[ri] = o;
        } else {
            float w0 = attnp[0], w1 = attnp[1], w2 = attnp[2], w3 = attnp[3];
            float4 e = reinterpret_cast<const float4*>(emb)[ri];
            uint2 v1 = reinterpret_cast<const uint2*>(y1)[ri];
            uint2 v2 = xv[ri];                 // y2 row of this node
            float4 r;
            r.x = w0 * e.x + w1 * h2lo(v1.x) + w2 * h2lo(v2.x) + w3 * a0;
            r.y = w0 * e.y + w1 * h2hi(v1.x) + w2 * h2hi(v2.x) + w3 * a1;
            r.z = w0 * e.z + w1 * h2lo(v1.y) + w2 * h2lo(v2.y) + w3 * a2;
            r.w = w0 * e.w + w1 * h2hi(v1.y) + w2 * h2hi(v2.y) + w3 * a3;
            reinterpret_cast<float4*>(out0)[ri] = e;
            reinterpret_cast<float4*>(acc)[ri] = r;
        }
    }
}

extern "C" void kernel_launch(void* const* d_in, const int* in_sizes, int n_in,
                              void* d_out, int out_size, void* d_ws, size_t ws_size,
                              hipStream_t stream) {
    const float* emb   = (const float*)d_in[0];
    const float* attw  = (const float*)d_in[1];
    const float* scale = (const float*)d_in[2];
    const float* attr  = (const float*)d_in[3];
    const int*   ei    = (const int*)d_in[4];
    const int* src = ei;
    const int* dst = ei + NE;

    float* out0 = (float*)d_out;
    float* acc  = out0 + (size_t)NN * ED;

    // workspace (~62.7 MB). part dead after k_place -> aliased by x0,y1.
    char* ws = (char*)d_ws;
    size_t off = 0;
    float*  attn   = (float*)(ws + off);  off += 256;
    int*    bcnt   = (int*)(ws + off);    off += 1024;
    int*    bstart = (int*)(ws + off);    off += 1024;
    int*    gcur   = (int*)(ws + off);    off += 1024;
    int*    pbsum  = (int*)(ws + off);    off += 1024;
    int*    pbase  = (int*)(ws + off);    off += 1024;
    float*  dinvf  = (float*)(ws + off);  off += ((size_t)NN * 4 + 255) & ~(size_t)255;
    int*    rowptr = (int*)(ws + off);    off += ((size_t)(NN + 1) * 4 + 255) & ~(size_t)255;
    unsigned long long* part = (unsigned long long*)(ws + off); off += (size_t)NE * 8;
    int*    es     = (int*)(ws + off);    off += (size_t)NEP * 4;
    __half* ew     = (__half*)(ws + off); off += (size_t)NEP * 2;
    unsigned short* y2 = (unsigned short*)(ws + off); off += (size_t)NN * ED * 2;
    unsigned short* x0 = (unsigned short*)part;                     // alias
    unsigned short* y1 = (unsigned short*)part + (size_t)NN * ED;   // alias

    const int VB = (NN * ED / 4) / 256;      // 6250 exact
    const int GB = (NN * ED) / 256;          // 25000 exact
    const int HB = (NE / 4 + 2047) / 2048;   // 391
    const int PB = (NE + CHUNK - 1) / CHUNK; // 391

    hipMemsetAsync(bcnt, 0, NBUCK * 4, stream);
    k_softmax<<<1, 1, 0, stream>>>(attw, attn);
    k_bcount<<<HB, 256, 0, stream>>>(dst, bcnt);
    k_bscan<<<1, 64, 0, stream>>>(bcnt, bstart, gcur);
    k_part<<<PB, PTH, 0, stream>>>(src, dst, attr, gcur, part);
    k_ndeg<<<NBUCK, 512, 0, stream>>>(bstart, part, rowptr, dinvf, pbsum);
    k_pbscan<<<1, 64, 0, stream>>>(pbsum, pbase, rowptr);
    k_place<<<NBUCK, 512, 0, stream>>>(bstart, pbase, pbsum, part, dinvf, scale, es, ew, rowptr);

    k_prep<<<VB, 256, 0, stream>>>(emb, x0);   // part dead; x0/y1 alias it

    k_gather<false><<<GB, 256, 0, stream>>>(rowptr, es, ew, x0, y1, nullptr, nullptr, nullptr, nullptr, nullptr);
    k_gather<false><<<GB, 256, 0, stream>>>(rowptr, es, ew, y1, y2, nullptr, nullptr, nullptr, nullptr, nullptr);
    k_gather<true><<<GB, 256, 0, stream>>>(rowptr, es, ew, y2, nullptr, y1, emb, attn, out0, acc);
}